// Round 2
// baseline (141.262 us; speedup 1.0000x reference)
//
#include <hip/hip_runtime.h>
#include <hip/hip_bf16.h>

// MPS log-trace: out[b] = log(trace(prod_{n=0..1023} A[s_idx[b,n]]))
// Strategy:
//   Kernel 1: build 256-entry table T[key] = A[b0]@A[b1]@...@A[b7] (fp32 in LDS),
//             stored as bf16 in MFMA A-fragment layout of T^T (transposed product).
//   Kernel 2: one wave per batch. carry M (f32x16 accum, 32x32 C-layout),
//             M <- T_j^T @ M for j=0..127 (trace(P^T)=trace(P)).
//             carry->B-fragment via 8x manual cvt_pk + 4x permlane32_swap.

#define BATCH   4096
#define N_SITES 1024
#define NKEYS   256
#define NSTEP   128   // 1024 sites / 8 per block

typedef __attribute__((ext_vector_type(8)))  short    short8;
typedef __attribute__((ext_vector_type(16))) float    f32x16;
typedef __attribute__((ext_vector_type(4)))  unsigned uint4v;

// f32 -> bf16 (round-to-nearest-even), pure bit ops (trivially copyable types only)
static __device__ __forceinline__ unsigned short f32_to_bf16(float f) {
  unsigned u = __builtin_bit_cast(unsigned, f);
  const unsigned rounding = 0x7FFFu + ((u >> 16) & 1u);
  return (unsigned short)((u + rounding) >> 16);
}
static __device__ __forceinline__ unsigned pack_bf16x2(float lo, float hi) {
  return (unsigned)f32_to_bf16(lo) | ((unsigned)f32_to_bf16(hi) << 16);
}

// ---------------------------------------------------------------------------
// Kernel 1: table build. 256 blocks (one per key) x 256 threads.
// ---------------------------------------------------------------------------
__global__ __launch_bounds__(256) void build_table_k(const float* __restrict__ A,
                                                     unsigned short* __restrict__ table) {
  __shared__ float As[2][32][32];
  __shared__ float M[2][32][32];
  const int key = blockIdx.x;
  const int t   = threadIdx.x;

  for (int i = t; i < 2 * 32 * 32; i += 256) ((float*)As)[i] = A[i];

  const int row = t >> 3;          // 0..31
  const int col = (t & 7) << 2;    // 0,4,...,28
  __syncthreads();

  {
    const int b0 = key & 1;
    for (int e = 0; e < 4; ++e) M[0][row][col + e] = As[b0][row][col + e];
  }
  __syncthreads();

  int cur = 0;
  for (int i = 1; i < 8; ++i) {
    const int bi = (key >> i) & 1;
    float a0 = 0.f, a1 = 0.f, a2 = 0.f, a3 = 0.f;
    for (int k = 0; k < 32; ++k) {
      const float m = M[cur][row][k];
      a0 += m * As[bi][k][col + 0];
      a1 += m * As[bi][k][col + 1];
      a2 += m * As[bi][k][col + 2];
      a3 += m * As[bi][k][col + 3];
    }
    M[cur ^ 1][row][col + 0] = a0;
    M[cur ^ 1][row][col + 1] = a1;
    M[cur ^ 1][row][col + 2] = a2;
    M[cur ^ 1][row][col + 3] = a3;
    __syncthreads();
    cur ^= 1;
  }

  // Write bf16 table entry in A-fragment layout of T^T:
  // for MFMA call c (K-slice), lane l, elem e: value = Tt[l&31][c*16+(l>>5)*8+e]
  //                                                  = M[c*16+(l>>5)*8+e][l&31]
  // ushort offset within entry: c*512 + l*8 + e   (entry stride 1024 ushorts)
  const int c    = t >> 7;         // 0..1
  const int l    = (t >> 1) & 63;  // lane
  const int e4   = (t & 1) << 2;   // 0 or 4
  const int rowm = l & 31;
  const int hi   = l >> 5;

  unsigned long long packed = 0;
  for (int e = 0; e < 4; ++e) {
    const int k = c * 16 + (hi << 3) + e4 + e;
    const unsigned short us = f32_to_bf16(M[cur][k][rowm]);
    packed |= (unsigned long long)us << (16 * e);
  }
  *reinterpret_cast<unsigned long long*>(table + (size_t)key * 1024 + c * 512 + l * 8 + e4) = packed;
}

// ---------------------------------------------------------------------------
// Kernel 2: chain contraction. 1024 blocks x 256 threads (4 waves, 1 batch/wave).
// ---------------------------------------------------------------------------
__global__ __launch_bounds__(256) void mps_chain_k(const float* __restrict__ s,
                                                   const unsigned short* __restrict__ table,
                                                   float* __restrict__ out) {
  const int wave = threadIdx.x >> 6;
  const int lane = threadIdx.x & 63;
  const int b    = blockIdx.x * 4 + wave;

  __shared__ unsigned char keys[4][NSTEP];

  // --- key extraction: lane covers sites 16*lane .. 16*lane+15 -> keys 2*lane, 2*lane+1
  const float*  srow = s + (size_t)b * N_SITES;
  const float4* s4   = reinterpret_cast<const float4*>(srow) + lane * 4;
  unsigned k0 = 0, k1 = 0;
#pragma unroll
  for (int q = 0; q < 4; ++q) {
    const float4 v = s4[q];
    const unsigned m = (v.x > 0.f ? 1u : 0u) | (v.y > 0.f ? 2u : 0u) |
                       (v.z > 0.f ? 4u : 0u) | (v.w > 0.f ? 8u : 0u);
    if (q < 2) k0 |= m << (q * 4);
    else       k1 |= m << ((q - 2) * 4);
  }
  keys[wave][2 * lane]     = (unsigned char)k0;
  keys[wave][2 * lane + 1] = (unsigned char)k1;
  __syncthreads();

  const int col = lane & 31;
  const int hi  = lane >> 5;

  // carry = I in 32x32 C-layout: acc[r] = M[(r&3)+8*(r>>2)+4*hi][col]
  f32x16 acc;
#pragma unroll
  for (int r = 0; r < 16; ++r) {
    const int rr = (r & 3) + 8 * (r >> 2) + 4 * hi;
    acc[r] = (rr == col) ? 1.f : 0.f;
  }

  const unsigned char* kw = keys[wave];
  unsigned key = kw[0];
  const unsigned short* ent = table + (size_t)key * 1024;
  uint4v a0 = *reinterpret_cast<const uint4v*>(ent + lane * 8);
  uint4v a1 = *reinterpret_cast<const uint4v*>(ent + 512 + lane * 8);

  for (int j = 0; j < NSTEP; ++j) {
    // prefetch next step's A fragments
    const unsigned nk = kw[(j + 1 < NSTEP) ? (j + 1) : j];
    const unsigned short* ne = table + (size_t)nk * 1024;
    const uint4v na0 = *reinterpret_cast<const uint4v*>(ne + lane * 8);
    const uint4v na1 = *reinterpret_cast<const uint4v*>(ne + 512 + lane * 8);

    // carry (f32, C-layout) -> bf16 B fragments
    unsigned pk[8];
#pragma unroll
    for (int i = 0; i < 8; ++i) {
      pk[i] = pack_bf16x2(acc[2 * i], acc[2 * i + 1]);
    }
    // permlane32_swap(a,b) -> ([a.lo|b.lo], [a.hi|b.hi])
    const auto s0 = __builtin_amdgcn_permlane32_swap((int)pk[0], (int)pk[2], false, false);
    const auto s1 = __builtin_amdgcn_permlane32_swap((int)pk[1], (int)pk[3], false, false);
    const auto s2 = __builtin_amdgcn_permlane32_swap((int)pk[4], (int)pk[6], false, false);
    const auto s3 = __builtin_amdgcn_permlane32_swap((int)pk[5], (int)pk[7], false, false);

    union { unsigned u[4]; short8 v; } B1, B2, A0u, A1u;
    B1.u[0] = (unsigned)s0[0]; B1.u[1] = (unsigned)s1[0];
    B1.u[2] = (unsigned)s0[1]; B1.u[3] = (unsigned)s1[1];
    B2.u[0] = (unsigned)s2[0]; B2.u[1] = (unsigned)s3[0];
    B2.u[2] = (unsigned)s2[1]; B2.u[3] = (unsigned)s3[1];
    union { uint4v q; short8 v; } ua0, ua1;
    ua0.q = a0; ua1.q = a1;
    A0u.v = ua0.v; A1u.v = ua1.v;

    f32x16 z;
#pragma unroll
    for (int r = 0; r < 16; ++r) z[r] = 0.f;

    f32x16 t1 = __builtin_amdgcn_mfma_f32_32x32x16_bf16(A0u.v, B1.v, z, 0, 0, 0);
    acc = __builtin_amdgcn_mfma_f32_32x32x16_bf16(A1u.v, B2.v, t1, 0, 0, 0);

    a0 = na0; a1 = na1;
  }

  // trace: lane holds diag element M[c][c] iff ((col>>2)&1)==hi, at reg (col&3)|((col>>3)<<2)
  float diag = 0.f;
#pragma unroll
  for (int r = 0; r < 16; ++r) {
    const int rr = (r & 3) + 8 * (r >> 2) + 4 * hi;
    if (rr == col) diag = acc[r];   // static index; at most one r matches
  }
  const bool has = (((col >> 2) & 1) == hi);
  diag = has ? diag : 0.f;
#pragma unroll
  for (int off = 32; off > 0; off >>= 1) diag += __shfl_down(diag, off, 64);
  if (lane == 0) out[b] = logf(diag);
}

// ---------------------------------------------------------------------------
extern "C" void kernel_launch(void* const* d_in, const int* in_sizes, int n_in,
                              void* d_out, int out_size, void* d_ws, size_t ws_size,
                              hipStream_t stream) {
  const float* s = (const float*)d_in[0];   // [4096,1024] f32
  const float* A = (const float*)d_in[1];   // [2,32,32] f32
  float* out = (float*)d_out;               // [4096] f32
  unsigned short* table = (unsigned short*)d_ws;  // 256 * 2048 B = 512 KiB

  build_table_k<<<NKEYS, 256, 0, stream>>>(A, table);
  mps_chain_k<<<BATCH / 4, 256, 0, stream>>>(s, table, out);
}

// Round 3
// 114.935 us; speedup vs baseline: 1.2291x; 1.2291x over previous
//
#include <hip/hip_runtime.h>
#include <hip/hip_bf16.h>

// MPS log-trace: out[b] = log(trace(prod_{n=0..1023} A[s_idx[b,n]]))
//   Kernel 1: 256-entry table T[key] = A[b0]@...@A[b7], bf16, A-fragment layout of T^T.
//   Kernel 2: one wave per batch; carry in MFMA C-layout f32; per step
//             carry->B-frag via 8x v_cvt_pk_bf16_f32 + 4x permlane32_swap,
//             two chained mfma_32x32x16_bf16; 2-deep fragment prefetch.

#define BATCH   4096
#define N_SITES 1024
#define NKEYS   256
#define NSTEP   128   // 1024 sites / 8 per block

typedef __attribute__((ext_vector_type(8)))  short    short8;
typedef __attribute__((ext_vector_type(16))) float    f32x16;
typedef __attribute__((ext_vector_type(4)))  unsigned uint4v;

// f32 -> bf16 RNE, scalar bit-op version (used on table-build path only)
static __device__ __forceinline__ unsigned short f32_to_bf16(float f) {
  unsigned u = __builtin_bit_cast(unsigned, f);
  const unsigned rounding = 0x7FFFu + ((u >> 16) & 1u);
  return (unsigned short)((u + rounding) >> 16);
}

// packed f32x2 -> bf16x2 in one VALU instruction (RNE; src0 -> low 16)
static __device__ __forceinline__ unsigned cvt_pk_bf16(float lo, float hi) {
  unsigned r;
  asm("v_cvt_pk_bf16_f32 %0, %1, %2" : "=v"(r) : "v"(lo), "v"(hi));
  return r;
}

// ---------------------------------------------------------------------------
// Kernel 1: table build. 256 blocks (one per key) x 256 threads.
// ---------------------------------------------------------------------------
__global__ __launch_bounds__(256) void build_table_k(const float* __restrict__ A,
                                                     unsigned short* __restrict__ table) {
  __shared__ float As[2][32][32];
  __shared__ float M[2][32][32];
  const int key = blockIdx.x;
  const int t   = threadIdx.x;

  for (int i = t; i < 2 * 32 * 32; i += 256) ((float*)As)[i] = A[i];

  const int row = t >> 3;          // 0..31
  const int col = (t & 7) << 2;    // 0,4,...,28
  __syncthreads();

  {
    const int b0 = key & 1;
    const float4 v = *reinterpret_cast<const float4*>(&As[b0][row][col]);
    *reinterpret_cast<float4*>(&M[0][row][col]) = v;
  }
  __syncthreads();

  int cur = 0;
  for (int i = 1; i < 8; ++i) {
    const int bi = (key >> i) & 1;
    float a0 = 0.f, a1 = 0.f, a2 = 0.f, a3 = 0.f;
    for (int k = 0; k < 32; ++k) {
      const float m  = M[cur][row][k];
      const float4 v = *reinterpret_cast<const float4*>(&As[bi][k][col]);
      a0 += m * v.x; a1 += m * v.y; a2 += m * v.z; a3 += m * v.w;
    }
    M[cur ^ 1][row][col + 0] = a0;
    M[cur ^ 1][row][col + 1] = a1;
    M[cur ^ 1][row][col + 2] = a2;
    M[cur ^ 1][row][col + 3] = a3;
    __syncthreads();
    cur ^= 1;
  }

  // bf16 entry in A-fragment layout of T^T:
  //   MFMA call c, lane l, elem e: value = M[c*16+(l>>5)*8+e][l&31]
  //   ushort offset: key*1024 + c*512 + l*8 + e
  const int c    = t >> 7;         // 0..1
  const int l    = (t >> 1) & 63;  // lane
  const int e4   = (t & 1) << 2;   // 0 or 4
  const int rowm = l & 31;
  const int hi   = l >> 5;

  unsigned long long packed = 0;
  for (int e = 0; e < 4; ++e) {
    const int k = c * 16 + (hi << 3) + e4 + e;
    const unsigned short us = f32_to_bf16(M[cur][k][rowm]);
    packed |= (unsigned long long)us << (16 * e);
  }
  *reinterpret_cast<unsigned long long*>(table + (size_t)key * 1024 + c * 512 + l * 8 + e4) = packed;
}

// ---------------------------------------------------------------------------
// Kernel 2: chain contraction. 1024 blocks x 256 threads (4 waves, 1 batch/wave).
// ---------------------------------------------------------------------------
__global__ __launch_bounds__(256) void mps_chain_k(const float* __restrict__ s,
                                                   const unsigned short* __restrict__ table,
                                                   float* __restrict__ out) {
  const int wave = threadIdx.x >> 6;
  const int lane = threadIdx.x & 63;
  const int b    = blockIdx.x * 4 + wave;

  __shared__ unsigned char keys[4][NSTEP + 8];   // padded so j+3 reads stay in-bounds

  // --- key extraction: lane covers sites 16*lane .. 16*lane+15 -> keys 2*lane, 2*lane+1
  const float*  srow = s + (size_t)b * N_SITES;
  const float4* s4   = reinterpret_cast<const float4*>(srow) + lane * 4;
  unsigned k0 = 0, k1 = 0;
#pragma unroll
  for (int q = 0; q < 4; ++q) {
    const float4 v = s4[q];
    const unsigned m = (v.x > 0.f ? 1u : 0u) | (v.y > 0.f ? 2u : 0u) |
                       (v.z > 0.f ? 4u : 0u) | (v.w > 0.f ? 8u : 0u);
    if (q < 2) k0 |= m << (q * 4);
    else       k1 |= m << ((q - 2) * 4);
  }
  keys[wave][2 * lane]     = (unsigned char)k0;
  keys[wave][2 * lane + 1] = (unsigned char)k1;
  if (lane < 8) keys[wave][NSTEP + lane] = 0;    // pad
  __syncthreads();

  const int col = lane & 31;
  const int hi  = lane >> 5;

  // carry = I in 32x32 C-layout: acc[r] = M[(r&3)+8*(r>>2)+4*hi][col]
  f32x16 acc;
#pragma unroll
  for (int r = 0; r < 16; ++r) {
    const int rr = (r & 3) + 8 * (r >> 2) + 4 * hi;
    acc[r] = (rr == col) ? 1.f : 0.f;
  }

  const unsigned char* kw = keys[wave];
  const unsigned long long laneoff = (unsigned long long)lane * 8;

  // 2-deep fragment prefetch pipeline
  unsigned kA = kw[0], kB = kw[1];
  unsigned kC = kw[2];                              // key for step j+2
  const unsigned short* e0 = table + (size_t)kA * 1024;
  const unsigned short* e1 = table + (size_t)kB * 1024;
  uint4v c0 = *reinterpret_cast<const uint4v*>(e0 + laneoff);
  uint4v c1 = *reinterpret_cast<const uint4v*>(e0 + 512 + laneoff);
  uint4v n0 = *reinterpret_cast<const uint4v*>(e1 + laneoff);
  uint4v n1 = *reinterpret_cast<const uint4v*>(e1 + 512 + laneoff);

#pragma unroll 4
  for (int j = 0; j < NSTEP; ++j) {
    // issue loads for step j+2 (key was ds_read one iteration ago)
    const unsigned short* ef = table + (size_t)kC * 1024;
    const uint4v f0 = *reinterpret_cast<const uint4v*>(ef + laneoff);
    const uint4v f1 = *reinterpret_cast<const uint4v*>(ef + 512 + laneoff);
    kC = kw[j + 3];                                 // key for next iteration's issue

    // carry (f32, C-layout) -> bf16 B fragments: 8 cvt_pk + 4 permlane32_swap
    unsigned pk[8];
#pragma unroll
    for (int i = 0; i < 8; ++i) pk[i] = cvt_pk_bf16(acc[2 * i], acc[2 * i + 1]);
    const auto s0 = __builtin_amdgcn_permlane32_swap((int)pk[0], (int)pk[2], false, false);
    const auto s1 = __builtin_amdgcn_permlane32_swap((int)pk[1], (int)pk[3], false, false);
    const auto s2 = __builtin_amdgcn_permlane32_swap((int)pk[4], (int)pk[6], false, false);
    const auto s3 = __builtin_amdgcn_permlane32_swap((int)pk[5], (int)pk[7], false, false);

    union { unsigned u[4]; short8 v; } B1, B2;
    B1.u[0] = (unsigned)s0[0]; B1.u[1] = (unsigned)s1[0];
    B1.u[2] = (unsigned)s0[1]; B1.u[3] = (unsigned)s1[1];
    B2.u[0] = (unsigned)s2[0]; B2.u[1] = (unsigned)s3[0];
    B2.u[2] = (unsigned)s2[1]; B2.u[3] = (unsigned)s3[1];

    union { uint4v q; short8 v; } ua0, ua1;
    ua0.q = c0; ua1.q = c1;

    f32x16 z;
#pragma unroll
    for (int r = 0; r < 16; ++r) z[r] = 0.f;

    f32x16 t1 = __builtin_amdgcn_mfma_f32_32x32x16_bf16(ua0.v, B1.v, z, 0, 0, 0);
    acc = __builtin_amdgcn_mfma_f32_32x32x16_bf16(ua1.v, B2.v, t1, 0, 0, 0);

    // rotate pipeline
    c0 = n0; c1 = n1; n0 = f0; n1 = f1;
  }

  // trace: lane holds diag element iff ((col>>2)&1)==hi
  float diag = 0.f;
#pragma unroll
  for (int r = 0; r < 16; ++r) {
    const int rr = (r & 3) + 8 * (r >> 2) + 4 * hi;
    if (rr == col) diag = acc[r];   // static index; at most one r matches
  }
  const bool has = (((col >> 2) & 1) == hi);
  diag = has ? diag : 0.f;
#pragma unroll
  for (int off = 32; off > 0; off >>= 1) diag += __shfl_down(diag, off, 64);
  if (lane == 0) out[b] = logf(diag);
}

// ---------------------------------------------------------------------------
extern "C" void kernel_launch(void* const* d_in, const int* in_sizes, int n_in,
                              void* d_out, int out_size, void* d_ws, size_t ws_size,
                              hipStream_t stream) {
  const float* s = (const float*)d_in[0];   // [4096,1024] f32
  const float* A = (const float*)d_in[1];   // [2,32,32] f32
  float* out = (float*)d_out;               // [4096] f32
  unsigned short* table = (unsigned short*)d_ws;  // 256 * 2048 B = 512 KiB

  build_table_k<<<NKEYS, 256, 0, stream>>>(A, table);
  mps_chain_k<<<BATCH / 4, 256, 0, stream>>>(s, table, out);
}

// Round 6
// 114.317 us; speedup vs baseline: 1.2357x; 1.0054x over previous
//
#include <hip/hip_runtime.h>
#include <hip/hip_bf16.h>

// MPS log-trace: out[b] = log(trace(prod_{n=0..1023} A[s_idx[b,n]]))
//   Kernel 1: 256-entry table T[key] = A[b0]@...@A[b7] (fp32 in LDS),
//             stored bf16 in MFMA A-fragment layout of T^T. (R3-proven, verbatim)
//   Kernel 2: TWO waves per batch (split-chain): wave w computes partial
//             product of its 64 steps with the R3-proven step body
//             (8x v_cvt_pk_bf16_f32 + 4x permlane32_swap + 2x mfma_32x32x16_bf16,
//              2-deep fragment prefetch). Combine: M^T = H@L,
//             trace = sum H[i,k]*L[k,i] via rotated-transpose LDS exchange.
// NOTE (R4/R5 bisect): adding __launch_bounds__(256,4) + readfirstlane table
// addressing + hoisted zero-C to the R3 chain produced NaN (garbage products).
// Cause not isolated; do NOT reintroduce as a bundle.

#define BATCH   4096
#define N_SITES 1024
#define NKEYS   256
#define NSTEP_H 64    // steps per wave (half chain)

typedef __attribute__((ext_vector_type(8)))  short    short8;
typedef __attribute__((ext_vector_type(16))) float    f32x16;
typedef __attribute__((ext_vector_type(4)))  unsigned uint4v;

// f32 -> bf16 RNE, bit-op version (table-build tail only)
static __device__ __forceinline__ unsigned short f32_to_bf16(float f) {
  unsigned u = __builtin_bit_cast(unsigned, f);
  const unsigned rounding = 0x7FFFu + ((u >> 16) & 1u);
  return (unsigned short)((u + rounding) >> 16);
}

// packed f32x2 -> bf16x2 in one VALU instruction (RNE; src0 -> low 16)
static __device__ __forceinline__ unsigned cvt_pk_bf16(float lo, float hi) {
  unsigned r;
  asm("v_cvt_pk_bf16_f32 %0, %1, %2" : "=v"(r) : "v"(lo), "v"(hi));
  return r;
}

// ---------------------------------------------------------------------------
// Kernel 1: table build. 256 blocks (one per key) x 256 threads. (R3-proven)
// ---------------------------------------------------------------------------
__global__ __launch_bounds__(256) void build_table_k(const float* __restrict__ A,
                                                     unsigned short* __restrict__ table) {
  __shared__ float As[2][32][32];
  __shared__ float M[2][32][32];
  const int key = blockIdx.x;
  const int t   = threadIdx.x;

  for (int i = t; i < 2 * 32 * 32; i += 256) ((float*)As)[i] = A[i];

  const int row = t >> 3;          // 0..31
  const int col = (t & 7) << 2;    // 0,4,...,28
  __syncthreads();

  {
    const int b0 = key & 1;
    const float4 v = *reinterpret_cast<const float4*>(&As[b0][row][col]);
    *reinterpret_cast<float4*>(&M[0][row][col]) = v;
  }
  __syncthreads();

  int cur = 0;
  for (int i = 1; i < 8; ++i) {
    const int bi = (key >> i) & 1;
    float a0 = 0.f, a1 = 0.f, a2 = 0.f, a3 = 0.f;
    for (int k = 0; k < 32; ++k) {
      const float m  = M[cur][row][k];
      const float4 v = *reinterpret_cast<const float4*>(&As[bi][k][col]);
      a0 += m * v.x; a1 += m * v.y; a2 += m * v.z; a3 += m * v.w;
    }
    M[cur ^ 1][row][col + 0] = a0;
    M[cur ^ 1][row][col + 1] = a1;
    M[cur ^ 1][row][col + 2] = a2;
    M[cur ^ 1][row][col + 3] = a3;
    __syncthreads();
    cur ^= 1;
  }

  // bf16 entry in A-fragment layout of T^T:
  //   MFMA call c, lane l, elem e: value = M[c*16+(l>>5)*8+e][l&31]
  //   ushort offset: key*1024 + c*512 + l*8 + e
  const int c    = t >> 7;         // 0..1
  const int l    = (t >> 1) & 63;  // lane
  const int e4   = (t & 1) << 2;   // 0 or 4
  const int rowm = l & 31;
  const int hi   = l >> 5;

  unsigned long long packed = 0;
  for (int e = 0; e < 4; ++e) {
    const int k = c * 16 + (hi << 3) + e4 + e;
    const unsigned short us = f32_to_bf16(M[cur][k][rowm]);
    packed |= (unsigned long long)us << (16 * e);
  }
  *reinterpret_cast<unsigned long long*>(table + (size_t)key * 1024 + c * 512 + l * 8 + e4) = packed;
}

// ---------------------------------------------------------------------------
// Kernel 2: split-chain contraction. 2048 blocks x 256 threads.
// Block = 2 pairs; pair = 2 waves; each wave does 64 steps of one batch chain.
// ---------------------------------------------------------------------------
__global__ __launch_bounds__(256) void mps_chain_k(const float* __restrict__ s,
                                                   const unsigned short* __restrict__ table,
                                                   float* __restrict__ out) {
  const int t    = threadIdx.x;
  const int pair = t >> 7;          // 0..1   (which batch within block)
  const int wv   = (t >> 6) & 1;    // 0..1   (which half of the chain)
  const int lane = t & 63;
  const int b    = blockIdx.x * 2 + pair;

  __shared__ unsigned char keys[2][128 + 8];   // per pair, padded for j+3 prefetch reads
  __shared__ float Ht[2][1024];                // wave1's product, transposed+rotated

  // --- key extraction: one key (8 sites) per lane; kidx = wv*64+lane
  const int kidx = wv * 64 + lane;
  const float4* s4 = reinterpret_cast<const float4*>(s) + (size_t)b * 256 + kidx * 2;
  const float4 va = s4[0];
  const float4 vb = s4[1];
  const unsigned key =
      (va.x > 0.f ? 1u : 0u)  | (va.y > 0.f ? 2u : 0u)  |
      (va.z > 0.f ? 4u : 0u)  | (va.w > 0.f ? 8u : 0u)  |
      (vb.x > 0.f ? 16u : 0u) | (vb.y > 0.f ? 32u : 0u) |
      (vb.z > 0.f ? 64u : 0u) | (vb.w > 0.f ? 128u : 0u);
  keys[pair][kidx] = (unsigned char)key;
  if (t < 16) keys[t >> 3][128 + (t & 7)] = 0;   // zero the pad region
  __syncthreads();

  const int col = lane & 31;
  const int hi  = lane >> 5;

  // carry = I in 32x32 C-layout: acc[r] = M[(r&3)+8*(r>>2)+4*hi][col]
  f32x16 acc;
#pragma unroll
  for (int r = 0; r < 16; ++r) {
    const int rr = (r & 3) + 8 * (r >> 2) + 4 * hi;
    acc[r] = (rr == col) ? 1.f : 0.f;
  }

  const unsigned char* kw = keys[pair] + wv * NSTEP_H;
  const unsigned long long laneoff = (unsigned long long)lane * 8;

  // 2-deep fragment prefetch pipeline (R3-proven form)
  unsigned kA = kw[0], kB = kw[1];
  unsigned kC = kw[2];                              // key for step j+2
  const unsigned short* e0 = table + (size_t)kA * 1024;
  const unsigned short* e1 = table + (size_t)kB * 1024;
  uint4v c0 = *reinterpret_cast<const uint4v*>(e0 + laneoff);
  uint4v c1 = *reinterpret_cast<const uint4v*>(e0 + 512 + laneoff);
  uint4v n0 = *reinterpret_cast<const uint4v*>(e1 + laneoff);
  uint4v n1 = *reinterpret_cast<const uint4v*>(e1 + 512 + laneoff);

#pragma unroll 4
  for (int j = 0; j < NSTEP_H; ++j) {
    // issue loads for step j+2
    const unsigned short* ef = table + (size_t)kC * 1024;
    const uint4v f0 = *reinterpret_cast<const uint4v*>(ef + laneoff);
    const uint4v f1 = *reinterpret_cast<const uint4v*>(ef + 512 + laneoff);
    kC = kw[j + 3];

    // carry (f32, C-layout) -> bf16 B fragments: 8 cvt_pk + 4 permlane32_swap
    unsigned pk[8];
#pragma unroll
    for (int i = 0; i < 8; ++i) pk[i] = cvt_pk_bf16(acc[2 * i], acc[2 * i + 1]);
    const auto s0 = __builtin_amdgcn_permlane32_swap((int)pk[0], (int)pk[2], false, false);
    const auto s1 = __builtin_amdgcn_permlane32_swap((int)pk[1], (int)pk[3], false, false);
    const auto s2 = __builtin_amdgcn_permlane32_swap((int)pk[4], (int)pk[6], false, false);
    const auto s3 = __builtin_amdgcn_permlane32_swap((int)pk[5], (int)pk[7], false, false);

    union { unsigned u[4]; short8 v; } B1, B2;
    B1.u[0] = (unsigned)s0[0]; B1.u[1] = (unsigned)s1[0];
    B1.u[2] = (unsigned)s0[1]; B1.u[3] = (unsigned)s1[1];
    B2.u[0] = (unsigned)s2[0]; B2.u[1] = (unsigned)s3[0];
    B2.u[2] = (unsigned)s2[1]; B2.u[3] = (unsigned)s3[1];

    union { uint4v q; short8 v; } ua0, ua1;
    ua0.q = c0; ua1.q = c1;

    f32x16 z;
#pragma unroll
    for (int r = 0; r < 16; ++r) z[r] = 0.f;

    f32x16 t1 = __builtin_amdgcn_mfma_f32_32x32x16_bf16(ua0.v, B1.v, z, 0, 0, 0);
    acc = __builtin_amdgcn_mfma_f32_32x32x16_bf16(ua1.v, B2.v, t1, 0, 0, 0);

    // rotate pipeline
    c0 = n0; c1 = n1; n0 = f0; n1 = f1;
  }

  // --- combine: M^T = H @ L (H = wave1 partial, L = wave0 partial)
  // trace(H@L) = sum_{i,k} H[i,k] * L[k,i].
  // Wave1 stores element H[a][b] (a=row(r,lane), b=col) at Ht[b*32 + ((a+b)&31)]
  // (rotation keeps both write and read conflict-free).
  if (wv == 1) {
#pragma unroll
    for (int r = 0; r < 16; ++r) {
      const int a = (r & 3) + 8 * (r >> 2) + 4 * hi;
      Ht[pair][col * 32 + ((a + col) & 31)] = acc[r];
    }
  }
  __syncthreads();
  if (wv == 0) {
    float dot = 0.f;
#pragma unroll
    for (int r = 0; r < 16; ++r) {
      const int k = (r & 3) + 8 * (r >> 2) + 4 * hi;   // L-element row
      // need H[i=col][k]: stored at Ht[k*32 + ((col+k)&31)]
      dot += acc[r] * Ht[pair][k * 32 + ((col + k) & 31)];
    }
#pragma unroll
    for (int off = 32; off > 0; off >>= 1) dot += __shfl_down(dot, off, 64);
    if (lane == 0) out[b] = logf(dot);
  }
}

// ---------------------------------------------------------------------------
extern "C" void kernel_launch(void* const* d_in, const int* in_sizes, int n_in,
                              void* d_out, int out_size, void* d_ws, size_t ws_size,
                              hipStream_t stream) {
  const float* s = (const float*)d_in[0];   // [4096,1024] f32
  const float* A = (const float*)d_in[1];   // [2,32,32] f32
  float* out = (float*)d_out;               // [4096] f32
  unsigned short* table = (unsigned short*)d_ws;  // 256 * 2048 B = 512 KiB

  build_table_k<<<NKEYS, 256, 0, stream>>>(A, table);
  mps_chain_k<<<BATCH / 2, 256, 0, stream>>>(s, table, out);
}